// Round 1
// baseline (261.226 us; speedup 1.0000x reference)
//
#include <hip/hip_runtime.h>
#include <hip/hip_bf16.h>

// Problem constants
#define BS   256
#define HH   32
#define WW   32
#define PIX  1024          // 32*32
#define CBAND 200
#define FEAT 64
#define NCOL 128           // Wk|Wv fused
#define ALPHA 0.2f
#define BETA  0.5f

__device__ __forceinline__ float lrelu(float v) { return v >= 0.f ? v : ALPHA * v; }

// ---------------------------------------------------------------------------
// Kernel 1: central pixel features.
// central1[b,f] = lrelu(x[b,16,16,:] @ Wk)[f]
// chalf[b,f]    = BETA * lrelu(central2[b,:] @ Wn^T)[f]
// ---------------------------------------------------------------------------
__global__ __launch_bounds__(64) void central_k(
    const float* __restrict__ x, const float* __restrict__ Wk,
    const float* __restrict__ Wv, const float* __restrict__ Wn,
    float* __restrict__ c1, float* __restrict__ chalf)
{
    int b = blockIdx.x;
    int f = threadIdx.x;                       // 64 threads
    __shared__ float xr[CBAND];
    __shared__ float c2s[FEAT];
    const float* xc = x + (size_t)b * (PIX * CBAND) + (16 * 32 + 16) * CBAND;
    for (int c = f; c < CBAND; c += 64) xr[c] = xc[c];
    __syncthreads();
    float a1 = 0.f, a2 = 0.f;
    #pragma unroll 4
    for (int c = 0; c < CBAND; ++c) {
        float xv = xr[c];
        a1 += xv * Wk[c * FEAT + f];
        a2 += xv * Wv[c * FEAT + f];
    }
    c1[b * FEAT + f] = lrelu(a1);
    c2s[f] = lrelu(a2);
    __syncthreads();
    float a3 = 0.f;
    #pragma unroll 8
    for (int g = 0; g < FEAT; ++g) a3 += c2s[g] * Wn[f * FEAT + g];
    chalf[b * FEAT + f] = BETA * lrelu(a3);
}

// ---------------------------------------------------------------------------
// Kernel 2: main GEMM.  262144 rows x 200 K x 128 N (cols 0..63 = Wk -> h1,
// cols 64..127 = Wv -> h2).  Per block: 64 rows, all 128 cols.
//   - x tile fully staged in LDS (stride 204 to keep conflicts 2-way/free)
//   - W staged in K-chunks of 8, double buffered
//   - thread micro-tile: 4 rows x 8 cols (rg = tid>>4, cg = tid&15)
// Epilogue: h1 -> mean_corr (transposed [p][b]), h2 -> ws (fp32 or bf16).
// ---------------------------------------------------------------------------
#define XSTR 204
#define KCH  8

template <bool H2F32>
__global__ __launch_bounds__(256) void gemm_main(
    const float* __restrict__ x, const float* __restrict__ Wk,
    const float* __restrict__ Wv, const float* __restrict__ c1,
    float* __restrict__ mcT, void* __restrict__ h2out)
{
    __shared__ float xs[64 * XSTR];
    __shared__ float wsh[2][KCH * NCOL];
    __shared__ float c1s[FEAT];

    const int tid = threadIdx.x;
    const int rg = tid >> 4;     // 0..15 -> rows rg*4 .. rg*4+3
    const int cg = tid & 15;     // 0..15 -> cols cg*8 .. cg*8+7
    const int row0 = blockIdx.x * 64;
    const int bb = row0 >> 10;   // batch (64 | 1024 so uniform per block)

    // stage x tile: 64 rows * 200 floats = 3200 float4, linear in global
    {
        const float4* xg4 = (const float4*)(x + (size_t)row0 * CBAND);
        for (int idx = tid; idx < 64 * 50; idx += 256) {
            float4 v = xg4[idx];
            int r = idx / 50, c4 = idx % 50;
            *(float4*)&xs[r * XSTR + c4 * 4] = v;
        }
    }
    if (tid < FEAT) c1s[tid] = c1[(size_t)bb * FEAT + tid];

    // W chunk loader: 8 x 128 floats, each thread one float4
    auto loadW = [&](int buf, int k0) {
        int kk = tid >> 5;            // 0..7
        int col = (tid & 31) * 4;     // 0..124
        int c = k0 + kk;
        float4 v;
        if (col < 64) v = *(const float4*)&Wk[c * FEAT + col];
        else          v = *(const float4*)&Wv[c * FEAT + (col - 64)];
        *(float4*)&wsh[buf][kk * NCOL + col] = v;
    };

    loadW(0, 0);
    __syncthreads();

    float acc[4][8];
    #pragma unroll
    for (int i = 0; i < 4; ++i)
        #pragma unroll
        for (int j = 0; j < 8; ++j) acc[i][j] = 0.f;

    const int NCHUNK = CBAND / KCH;   // 25
    for (int ch = 0; ch < NCHUNK; ++ch) {
        int buf = ch & 1;
        if (ch + 1 < NCHUNK) loadW(buf ^ 1, (ch + 1) * KCH);
        #pragma unroll
        for (int k = 0; k < KCH; ++k) {
            int kg = ch * KCH + k;
            float xv[4];
            #pragma unroll
            for (int i = 0; i < 4; ++i) xv[i] = xs[(rg * 4 + i) * XSTR + kg];
            float4 wa = *(float4*)&wsh[buf][k * NCOL + cg * 8];
            float4 wb = *(float4*)&wsh[buf][k * NCOL + cg * 8 + 4];
            float wv[8] = {wa.x, wa.y, wa.z, wa.w, wb.x, wb.y, wb.z, wb.w};
            #pragma unroll
            for (int i = 0; i < 4; ++i)
                #pragma unroll
                for (int j = 0; j < 8; ++j) acc[i][j] += xv[i] * wv[j];
        }
        __syncthreads();
    }

    // epilogue
    #pragma unroll
    for (int i = 0; i < 4; ++i) {
        int grow = row0 + rg * 4 + i;
        int p = grow & (PIX - 1);
        float v[8];
        #pragma unroll
        for (int j = 0; j < 8; ++j) v[j] = lrelu(acc[i][j]);

        // h1 half: dot with central1, reduce across cg 0..7 (lane bits 0..2)
        float part = 0.f;
        #pragma unroll
        for (int j = 0; j < 8; ++j) part += v[j] * c1s[(cg & 7) * 8 + j];
        part += __shfl_xor(part, 1);
        part += __shfl_xor(part, 2);
        part += __shfl_xor(part, 4);
        if (cg == 0) mcT[(size_t)p * BS + bb] = part * (1.f / FEAT);

        if (cg >= 8) {   // h2 half: store
            int f = (cg - 8) * 8;
            size_t idx = (size_t)grow * FEAT + f;
            if (H2F32) {
                float* h2 = (float*)h2out;
                *(float4*)&h2[idx]     = make_float4(v[0], v[1], v[2], v[3]);
                *(float4*)&h2[idx + 4] = make_float4(v[4], v[5], v[6], v[7]);
            } else {
                __hip_bfloat16 t[8];
                #pragma unroll
                for (int j = 0; j < 8; ++j) t[j] = __float2bfloat16(v[j]);
                *(int4*)&(((__hip_bfloat16*)h2out)[idx]) = *(int4*)t;
            }
        }
    }
}

// ---------------------------------------------------------------------------
// Kernel 3: softmax over batch axis, per pixel.  mcT layout [p][b], in-place.
// ---------------------------------------------------------------------------
__global__ __launch_bounds__(256) void softmax_b(float* __restrict__ mcT)
{
    int p = blockIdx.x, t = threadIdx.x;
    float* col = mcT + (size_t)p * BS;
    float v = col[t];
    float m = v;
    #pragma unroll
    for (int o = 32; o > 0; o >>= 1) m = fmaxf(m, __shfl_xor(m, o));
    __shared__ float r1[4], r2[4];
    int w = t >> 6, l = t & 63;
    if (l == 0) r1[w] = m;
    __syncthreads();
    m = fmaxf(fmaxf(r1[0], r1[1]), fmaxf(r1[2], r1[3]));
    float e = expf(v - m);
    float s = e;
    #pragma unroll
    for (int o = 32; o > 0; o >>= 1) s += __shfl_xor(s, o);
    if (l == 0) r2[w] = s;
    __syncthreads();
    s = r2[0] + r2[1] + r2[2] + r2[3];
    col[t] = e / s;
}

// ---------------------------------------------------------------------------
// Kernel 4: neighbour_feat[b,f] = sum_p h2[b,p,f] * attn[p][b]; final blend.
// One block per batch. tid -> f = tid&63, chunk = tid>>6 (4 chunks of 256 p).
// ---------------------------------------------------------------------------
template <bool H2F32>
__global__ __launch_bounds__(256) void neighbour_k(
    const void* __restrict__ h2in, const float* __restrict__ attnT,
    const float* __restrict__ chalf, float* __restrict__ out)
{
    int b = blockIdx.x, tid = threadIdx.x;
    __shared__ float att[PIX];
    __shared__ float part[4][FEAT];
    for (int p = tid; p < PIX; p += 256) att[p] = attnT[(size_t)p * BS + b];
    __syncthreads();
    int f = tid & 63, ck = tid >> 6;
    float acc = 0.f;
    if (H2F32) {
        const float* h2 = (const float*)h2in + (size_t)b * PIX * FEAT;
        for (int p = ck * 256; p < ck * 256 + 256; ++p)
            acc += h2[p * FEAT + f] * att[p];
    } else {
        const __hip_bfloat16* h2 = (const __hip_bfloat16*)h2in + (size_t)b * PIX * FEAT;
        for (int p = ck * 256; p < ck * 256 + 256; ++p)
            acc += __bfloat162float(h2[p * FEAT + f]) * att[p];
    }
    part[ck][f] = acc;
    __syncthreads();
    if (tid < FEAT) {
        float nb = part[0][tid] + part[1][tid] + part[2][tid] + part[3][tid];
        out[(size_t)b * FEAT + tid] = chalf[(size_t)b * FEAT + tid] + (1.f - BETA) * nb;
    }
}

// ---------------------------------------------------------------------------
extern "C" void kernel_launch(void* const* d_in, const int* in_sizes, int n_in,
                              void* d_out, int out_size, void* d_ws, size_t ws_size,
                              hipStream_t stream)
{
    const float* x  = (const float*)d_in[0];
    const float* Wk = (const float*)d_in[1];
    const float* Wv = (const float*)d_in[2];
    const float* Wn = (const float*)d_in[3];
    float* out = (float*)d_out;

    float* ws    = (float*)d_ws;
    float* c1    = ws;                     // 256*64
    float* chalf = ws + BS * FEAT;         // 256*64
    float* mcT   = ws + 2 * BS * FEAT;     // 1024*256  (becomes attn in-place)
    void*  h2    = (void*)(ws + 2 * BS * FEAT + PIX * BS);

    const size_t head_f = 2 * BS * FEAT + (size_t)PIX * BS;       // floats
    const size_t h2_elems = (size_t)BS * PIX * FEAT;              // 16.7M
    const bool h2f32 = ws_size >= (head_f + h2_elems) * sizeof(float);

    central_k<<<BS, 64, 0, stream>>>(x, Wk, Wv, Wn, c1, chalf);

    const int nblocks = (BS * PIX) / 64;   // 4096
    if (h2f32) gemm_main<true ><<<nblocks, 256, 0, stream>>>(x, Wk, Wv, c1, mcT, h2);
    else       gemm_main<false><<<nblocks, 256, 0, stream>>>(x, Wk, Wv, c1, mcT, h2);

    softmax_b<<<PIX, 256, 0, stream>>>(mcT);

    if (h2f32) neighbour_k<true ><<<BS, 256, 0, stream>>>(h2, mcT, chalf, out);
    else       neighbour_k<false><<<BS, 256, 0, stream>>>(h2, mcT, chalf, out);
}

// Round 2
// 112.799 us; speedup vs baseline: 2.3159x; 2.3159x over previous
//
#include <hip/hip_runtime.h>
#include <hip/hip_bf16.h>

#define BS    256
#define PIX   1024
#define CBAND 200
#define NK    7            // K-steps of 32 (K padded 200 -> 224)
#define FEAT  64
#define ALPHA 0.2f
#define BETA  0.5f
#define XSTR  232          // LDS row stride in bf16 elements (16B-aligned, conflict-free)

typedef __attribute__((ext_vector_type(8))) short bf16x8;   // MFMA A/B fragment (4 VGPR)
typedef __attribute__((ext_vector_type(4))) float f32x4;    // MFMA C/D fragment

__device__ __forceinline__ float lrelu(float v) { return v >= 0.f ? v : ALPHA * v; }
__device__ __forceinline__ float bf2f(short s) {
    unsigned int u = ((unsigned int)(unsigned short)s) << 16;
    return __uint_as_float(u);
}

// ---------------------------------------------------------------------------
// Kernel 0: pack Wk||Wv (fp32, 200x64 each) into bf16 B-fragments.
// Layout: Wb[((ks*8 + nf)*64 + lane)*8 + i] = W[k][c], k = ks*32 + (lane>>4)*8 + i,
// c = nf*16 + (lane&15); zero for k >= 200.  One dwordx4 per lane per fragment.
// ---------------------------------------------------------------------------
__global__ __launch_bounds__(64) void wprep_k(
    const float* __restrict__ Wk, const float* __restrict__ Wv,
    unsigned short* __restrict__ Wb)
{
    int l  = threadIdx.x;
    int nf = blockIdx.x & 7;
    int ks = blockIdx.x >> 3;
    int c  = nf * 16 + (l & 15);
    int k0 = ks * 32 + (l >> 4) * 8;
    __attribute__((aligned(16))) unsigned short o[8];
    #pragma unroll
    for (int i = 0; i < 8; ++i) {
        int k = k0 + i;
        float w = 0.f;
        if (k < CBAND) w = (c < 64) ? Wk[k * 64 + c] : Wv[k * 64 + (c - 64)];
        unsigned int u = __float_as_uint(w);
        u += 0x7FFFu + ((u >> 16) & 1u);          // RNE to bf16 (inputs never NaN)
        o[i] = (unsigned short)(u >> 16);
    }
    *(uint4*)&Wb[((size_t)blockIdx.x * 64 + l) * 8] = *(uint4*)o;
}

// ---------------------------------------------------------------------------
// Kernel 1: central pixel features (fp32 exact).
// c1[b,f] = lrelu(x[b,16,16,:] @ Wk); chalf[b,f] = BETA*lrelu((lrelu(x_c@Wv)) @ Wn^T)
// ---------------------------------------------------------------------------
__global__ __launch_bounds__(64) void central_k(
    const float* __restrict__ x, const float* __restrict__ Wk,
    const float* __restrict__ Wv, const float* __restrict__ Wn,
    float* __restrict__ c1, float* __restrict__ chalf)
{
    int b = blockIdx.x;
    int f = threadIdx.x;
    __shared__ float xr[CBAND];
    __shared__ float c2s[FEAT];
    const float* xc = x + (size_t)b * (PIX * CBAND) + (16 * 32 + 16) * CBAND;
    for (int c = f; c < CBAND; c += 64) xr[c] = xc[c];
    __syncthreads();
    float a1 = 0.f, a2 = 0.f;
    #pragma unroll 4
    for (int c = 0; c < CBAND; ++c) {
        float xv = xr[c];
        a1 += xv * Wk[c * FEAT + f];
        a2 += xv * Wv[c * FEAT + f];
    }
    c1[b * FEAT + f] = lrelu(a1);
    c2s[f] = lrelu(a2);
    __syncthreads();
    float a3 = 0.f;
    #pragma unroll 8
    for (int g = 0; g < FEAT; ++g) a3 += c2s[g] * Wn[f * FEAT + g];
    chalf[b * FEAT + f] = BETA * lrelu(a3);
}

// ---------------------------------------------------------------------------
// Kernel 2: MFMA GEMM. 262144 rows x K=224(pad) x N=128.
// Block: 128 rows, 4 waves; wave tile 32 rows x 128 cols via 16x16x32 bf16 MFMA.
// x staged once fp32->bf16 into LDS; B fragments streamed from L2, dbuf.
// Epilogue: nf 0..3 -> mean_corr (transposed [p][b]); nf 4..7 -> h2[b][f][p] bf16.
// ---------------------------------------------------------------------------
__global__ __launch_bounds__(256, 2) void gemm_mfma(
    const float* __restrict__ x, const unsigned short* __restrict__ Wb,
    const float* __restrict__ c1, float* __restrict__ mcT,
    unsigned short* __restrict__ h2)
{
    __shared__ unsigned short xs[128 * XSTR];
    __shared__ float c1s[FEAT];

    const int tid  = threadIdx.x;
    const int l    = tid & 63;
    const int w    = tid >> 6;
    const int row0 = blockIdx.x * 128;
    const int bb   = row0 >> 10;          // 128 | 1024: one batch per block

    const bf16x8* wbv = (const bf16x8*)Wb;
    bf16x8 bq[2][8];
    #pragma unroll
    for (int nf = 0; nf < 8; ++nf) bq[0][nf] = wbv[nf * 64 + l];   // ks=0 prefetch

    // stage x tile (128 rows x 200 f32) -> bf16 LDS, coalesced float4 stream
    #pragma unroll 5
    for (int j = 0; j < 25; ++j) {
        int idx = tid + j * 256;          // 0..6399
        int row = idx / 50;
        int c4  = idx - row * 50;
        float4 v = *(const float4*)(x + (size_t)(row0 + row) * CBAND + c4 * 4);
        __hip_bfloat162 p0 = __float22bfloat162_rn(make_float2(v.x, v.y));
        __hip_bfloat162 p1 = __float22bfloat162_rn(make_float2(v.z, v.w));
        uint2 pk;
        pk.x = *(unsigned int*)&p0;
        pk.y = *(unsigned int*)&p1;
        *(uint2*)&xs[row * XSTR + c4 * 4] = pk;
    }
    if (tid < 128) {                      // zero-pad k in [200, 232)
        uint4 z = make_uint4(0, 0, 0, 0);
        #pragma unroll
        for (int q = 0; q < 4; ++q) *(uint4*)&xs[tid * XSTR + 200 + q * 8] = z;
    }
    if (tid < FEAT) c1s[tid] = c1[bb * FEAT + tid];
    __syncthreads();

    f32x4 acc[2][8];
    #pragma unroll
    for (int mi = 0; mi < 2; ++mi)
        #pragma unroll
        for (int nf = 0; nf < 8; ++nf) acc[mi][nf] = (f32x4){0.f, 0.f, 0.f, 0.f};

    const int arow = w * 32 + (l & 15);
    const int kofs = (l >> 4) * 8;

    #pragma unroll
    for (int ks = 0; ks < NK; ++ks) {
        if (ks + 1 < NK) {
            #pragma unroll
            for (int nf = 0; nf < 8; ++nf)
                bq[(ks + 1) & 1][nf] = wbv[((ks + 1) * 8 + nf) * 64 + l];
        }
        bf16x8 a0 = *(const bf16x8*)&xs[arow * XSTR + ks * 32 + kofs];
        bf16x8 a1 = *(const bf16x8*)&xs[(arow + 16) * XSTR + ks * 32 + kofs];
        #pragma unroll
        for (int nf = 0; nf < 8; ++nf) {
            bf16x8 b = bq[ks & 1][nf];
            acc[0][nf] = __builtin_amdgcn_mfma_f32_16x16x32_bf16(a0, b, acc[0][nf], 0, 0, 0);
            acc[1][nf] = __builtin_amdgcn_mfma_f32_16x16x32_bf16(a1, b, acc[1][nf], 0, 0, 0);
        }
    }

    // ---- epilogue ----
    const int g  = l >> 4;                // D row group
    const int cl = l & 15;                // D col within fragment

    // h1 (nf 0..3): mean_corr[p][b] = mean_f(lrelu(h1) * c1)
    #pragma unroll
    for (int mi = 0; mi < 2; ++mi) {
        #pragma unroll
        for (int r = 0; r < 4; ++r) {
            float part = 0.f;
            #pragma unroll
            for (int nf = 0; nf < 4; ++nf)
                part += lrelu(acc[mi][nf][r]) * c1s[nf * 16 + cl];
            part += __shfl_xor(part, 1);
            part += __shfl_xor(part, 2);
            part += __shfl_xor(part, 4);
            part += __shfl_xor(part, 8);
            if (cl == 0) {
                int grow = row0 + w * 32 + mi * 16 + g * 4 + r;
                int p = grow & (PIX - 1);
                mcT[(size_t)p * BS + bb] = part * (1.f / 64.f);
            }
        }
    }

    // h2 (nf 4..7): store lrelu as bf16, layout h2[b][f][p]; 4 consecutive p per lane
    #pragma unroll
    for (int mi = 0; mi < 2; ++mi) {
        int p0 = (row0 & (PIX - 1)) + w * 32 + mi * 16 + g * 4;
        #pragma unroll
        for (int nf = 4; nf < 8; ++nf) {
            int f = (nf - 4) * 16 + cl;
            float v0 = lrelu(acc[mi][nf][0]);
            float v1 = lrelu(acc[mi][nf][1]);
            float v2 = lrelu(acc[mi][nf][2]);
            float v3 = lrelu(acc[mi][nf][3]);
            __hip_bfloat162 q0 = __float22bfloat162_rn(make_float2(v0, v1));
            __hip_bfloat162 q1 = __float22bfloat162_rn(make_float2(v2, v3));
            uint2 pk;
            pk.x = *(unsigned int*)&q0;
            pk.y = *(unsigned int*)&q1;
            *(uint2*)&h2[(((size_t)bb * 64 + f) << 10) + p0] = pk;
        }
    }
}

// ---------------------------------------------------------------------------
// Kernel 3: softmax over batch per pixel; mcT[p][b] -> attnN[b][p]
// ---------------------------------------------------------------------------
__global__ __launch_bounds__(256) void softmax_b(
    const float* __restrict__ mcT, float* __restrict__ attnN)
{
    int p = blockIdx.x, t = threadIdx.x;
    float v = mcT[(size_t)p * BS + t];
    float m = v;
    #pragma unroll
    for (int o = 32; o > 0; o >>= 1) m = fmaxf(m, __shfl_xor(m, o));
    __shared__ float r1[4], r2[4];
    int w = t >> 6, lz = t & 63;
    if (lz == 0) r1[w] = m;
    __syncthreads();
    m = fmaxf(fmaxf(r1[0], r1[1]), fmaxf(r1[2], r1[3]));
    float e = expf(v - m);
    float s = e;
    #pragma unroll
    for (int o = 32; o > 0; o >>= 1) s += __shfl_xor(s, o);
    if (lz == 0) r2[w] = s;
    __syncthreads();
    s = r2[0] + r2[1] + r2[2] + r2[3];
    attnN[(size_t)t * PIX + p] = e / s;
}

// ---------------------------------------------------------------------------
// Kernel 4: neighbour[b,f] = sum_p h2[b][f][p] * attn[b][p]; blend with chalf.
// Block per batch; wave w owns f = w*16 + j; att hoisted to 16 regs/lane.
// ---------------------------------------------------------------------------
__global__ __launch_bounds__(256) void neighbour_k(
    const unsigned short* __restrict__ h2, const float* __restrict__ attnN,
    const float* __restrict__ chalf, float* __restrict__ out)
{
    int b = blockIdx.x, tid = threadIdx.x;
    int l = tid & 63, w = tid >> 6;
    __shared__ float att[PIX];
    for (int p = tid; p < PIX; p += 256) att[p] = attnN[(size_t)b * PIX + p];
    __syncthreads();

    float av[16];
    #pragma unroll
    for (int i = 0; i < 8; ++i) av[i]     = att[l * 8 + i];
    #pragma unroll
    for (int i = 0; i < 8; ++i) av[8 + i] = att[512 + l * 8 + i];

    const unsigned short* hb = h2 + ((size_t)b * 64) * 1024;
    for (int j = 0; j < 16; ++j) {
        int f = w * 16 + j;
        const unsigned short* hf = hb + (size_t)f * 1024;
        bf16x8 h0 = *(const bf16x8*)&hf[l * 8];
        bf16x8 h1 = *(const bf16x8*)&hf[512 + l * 8];
        float acc = 0.f;
        #pragma unroll
        for (int i = 0; i < 8; ++i) acc += bf2f(h0[i]) * av[i];
        #pragma unroll
        for (int i = 0; i < 8; ++i) acc += bf2f(h1[i]) * av[8 + i];
        #pragma unroll
        for (int o = 32; o > 0; o >>= 1) acc += __shfl_xor(acc, o);
        if (l == 0)
            out[b * FEAT + f] = chalf[b * FEAT + f] + (1.f - BETA) * acc;
    }
}

// ---------------------------------------------------------------------------
extern "C" void kernel_launch(void* const* d_in, const int* in_sizes, int n_in,
                              void* d_out, int out_size, void* d_ws, size_t ws_size,
                              hipStream_t stream)
{
    const float* x  = (const float*)d_in[0];
    const float* Wk = (const float*)d_in[1];
    const float* Wv = (const float*)d_in[2];
    const float* Wn = (const float*)d_in[3];
    float* out = (float*)d_out;

    float* ws    = (float*)d_ws;
    float* c1    = ws;                                   // 16384 f
    float* chalf = ws + 16384;                           // 16384 f
    float* mcT   = ws + 32768;                           // 262144 f  [p][b]
    float* attnN = ws + 294912;                          // 262144 f  [b][p]
    unsigned short* Wb = (unsigned short*)(ws + 557056); // 28672 u16 (57344 B)
    unsigned short* h2 = (unsigned short*)((char*)d_ws + 2285568); // 33.5 MB [b][f][p]

    wprep_k  <<<56,   64, 0, stream>>>(Wk, Wv, Wb);
    central_k<<<BS,   64, 0, stream>>>(x, Wk, Wv, Wn, c1, chalf);
    gemm_mfma<<<2048, 256, 0, stream>>>(x, Wb, c1, mcT, h2);
    softmax_b<<<PIX,  256, 0, stream>>>(mcT, attnN);
    neighbour_k<<<BS, 256, 0, stream>>>(h2, attnN, chalf, out);
}

// Round 3
// 102.869 us; speedup vs baseline: 2.5394x; 1.0965x over previous
//
#include <hip/hip_runtime.h>
#include <hip/hip_bf16.h>

#define BS    256
#define PIX   1024
#define CBAND 200
#define NK    7            // K-steps of 32 (K padded 200 -> 224)
#define FEAT  64
#define ALPHA 0.2f
#define BETA  0.5f
#define XSTR  232          // LDS row stride in bf16 elems (16B-aligned)

typedef __attribute__((ext_vector_type(8))) short bf16x8;   // MFMA A/B fragment
typedef __attribute__((ext_vector_type(4))) float f32x4;    // MFMA C/D fragment

__device__ __forceinline__ float lrelu(float v) { return v >= 0.f ? v : ALPHA * v; }
__device__ __forceinline__ float bf2f(short s) {
    unsigned int u = ((unsigned int)(unsigned short)s) << 16;
    return __uint_as_float(u);
}

// ---------------------------------------------------------------------------
// Kernel 0 (fused prep): blocks 0..55 pack Wk||Wv into bf16 B-fragments;
// blocks 56..311 compute central-pixel features (fp32 exact).
// Wb layout: Wb[((ks*8+nf)*64 + lane)*8 + i] = W[k][c],
//   k = ks*32 + (lane>>4)*8 + i, c = nf*16 + (lane&15), zero for k >= 200.
// ---------------------------------------------------------------------------
__global__ __launch_bounds__(64) void prep_k(
    const float* __restrict__ x, const float* __restrict__ Wk,
    const float* __restrict__ Wv, const float* __restrict__ Wn,
    unsigned short* __restrict__ Wb, float* __restrict__ c1,
    float* __restrict__ chalf)
{
    __shared__ float xr[CBAND];
    __shared__ float c2s[FEAT];
    int l = threadIdx.x;
    if (blockIdx.x < 56) {
        int bid = blockIdx.x;
        int nf = bid & 7;
        int ks = bid >> 3;
        int c  = nf * 16 + (l & 15);
        int k0 = ks * 32 + (l >> 4) * 8;
        __attribute__((aligned(16))) unsigned short o[8];
        #pragma unroll
        for (int i = 0; i < 8; ++i) {
            int k = k0 + i;
            float w = 0.f;
            if (k < CBAND) w = (c < 64) ? Wk[k * 64 + c] : Wv[k * 64 + (c - 64)];
            unsigned int u = __float_as_uint(w);
            u += 0x7FFFu + ((u >> 16) & 1u);      // RNE to bf16
            o[i] = (unsigned short)(u >> 16);
        }
        *(uint4*)&Wb[((size_t)bid * 64 + l) * 8] = *(uint4*)o;
        return;
    }
    int b = blockIdx.x - 56;
    int f = l;
    const float* xc = x + (size_t)b * (PIX * CBAND) + (16 * 32 + 16) * CBAND;
    for (int c = f; c < CBAND; c += 64) xr[c] = xc[c];
    __syncthreads();
    float a1 = 0.f, a2 = 0.f;
    #pragma unroll 4
    for (int c = 0; c < CBAND; ++c) {
        float xv = xr[c];
        a1 += xv * Wk[c * FEAT + f];
        a2 += xv * Wv[c * FEAT + f];
    }
    c1[b * FEAT + f] = lrelu(a1);
    c2s[f] = lrelu(a2);
    __syncthreads();
    float a3 = 0.f;
    #pragma unroll 8
    for (int g = 0; g < FEAT; ++g) a3 += c2s[g] * Wn[f * FEAT + g];
    chalf[b * FEAT + f] = BETA * lrelu(a3);
}

// ---------------------------------------------------------------------------
// Kernel 1: MFMA GEMM. 262144 rows x K=224(pad) x N=128.
// Block: 64 rows, 4 waves; wave tile 16 rows x 128 cols (16x16x32 bf16 MFMA).
// LDS ~30 KB -> 5 blocks/CU for deep load pipelining (was 2 at 128 rows).
// Epilogue: nf 0..3 -> mean_corr (transposed [p][b]); nf 4..7 -> h2[b][f][p].
// ---------------------------------------------------------------------------
__global__ __launch_bounds__(256) void gemm_mfma(
    const float* __restrict__ x, const unsigned short* __restrict__ Wb,
    const float* __restrict__ c1, float* __restrict__ mcT,
    unsigned short* __restrict__ h2)
{
    __shared__ unsigned short xs[64 * XSTR];
    __shared__ float c1s[FEAT];

    const int tid  = threadIdx.x;
    const int l    = tid & 63;
    const int w    = tid >> 6;
    const int row0 = blockIdx.x * 64;
    const int bb   = row0 >> 10;          // 64 | 1024: one batch per block

    const bf16x8* wbv = (const bf16x8*)Wb;
    bf16x8 bq[2][8];
    #pragma unroll
    for (int nf = 0; nf < 8; ++nf) bq[0][nf] = wbv[nf * 64 + l];   // ks=0

    // stage x tile (64 rows x 200 f32) -> bf16 LDS, linear float4 stream
    for (int idx = tid; idx < 64 * 50; idx += 256) {
        int row = idx / 50;
        int c4  = idx - row * 50;
        float4 v = *(const float4*)(x + (size_t)(row0 + row) * CBAND + c4 * 4);
        __hip_bfloat162 p0 = __float22bfloat162_rn(make_float2(v.x, v.y));
        __hip_bfloat162 p1 = __float22bfloat162_rn(make_float2(v.z, v.w));
        uint2 pk;
        pk.x = *(unsigned int*)&p0;
        pk.y = *(unsigned int*)&p1;
        *(uint2*)&xs[row * XSTR + c4 * 4] = pk;
    }
    if (tid < 64) {                       // zero-pad k in [200, 232)
        uint4 z = make_uint4(0, 0, 0, 0);
        #pragma unroll
        for (int q = 0; q < 4; ++q) *(uint4*)&xs[tid * XSTR + 200 + q * 8] = z;
    }
    if (tid < FEAT) c1s[tid] = c1[bb * FEAT + tid];
    __syncthreads();

    f32x4 acc[8];
    #pragma unroll
    for (int nf = 0; nf < 8; ++nf) acc[nf] = (f32x4){0.f, 0.f, 0.f, 0.f};

    const int arow = w * 16 + (l & 15);
    const int kofs = (l >> 4) * 8;

    #pragma unroll
    for (int ks = 0; ks < NK; ++ks) {
        if (ks + 1 < NK) {
            #pragma unroll
            for (int nf = 0; nf < 8; ++nf)
                bq[(ks + 1) & 1][nf] = wbv[((ks + 1) * 8 + nf) * 64 + l];
        }
        bf16x8 a0 = *(const bf16x8*)&xs[arow * XSTR + ks * 32 + kofs];
        #pragma unroll
        for (int nf = 0; nf < 8; ++nf)
            acc[nf] = __builtin_amdgcn_mfma_f32_16x16x32_bf16(a0, bq[ks & 1][nf], acc[nf], 0, 0, 0);
    }

    // ---- epilogue ----
    const int g  = l >> 4;                // D row group
    const int cl = l & 15;                // D col within fragment

    // h1 (nf 0..3): mean_corr[p][b] = mean_f(lrelu(h1) * c1)
    #pragma unroll
    for (int r = 0; r < 4; ++r) {
        float part = 0.f;
        #pragma unroll
        for (int nf = 0; nf < 4; ++nf)
            part += lrelu(acc[nf][r]) * c1s[nf * 16 + cl];
        part += __shfl_xor(part, 1);
        part += __shfl_xor(part, 2);
        part += __shfl_xor(part, 4);
        part += __shfl_xor(part, 8);
        if (cl == 0) {
            int grow = row0 + w * 16 + g * 4 + r;
            int p = grow & (PIX - 1);
            mcT[(size_t)p * BS + bb] = part * (1.f / 64.f);
        }
    }

    // h2 (nf 4..7): store lrelu as bf16, layout h2[b][f][p]; 4 consecutive p
    {
        int p0 = (row0 & (PIX - 1)) + w * 16 + g * 4;
        #pragma unroll
        for (int nf = 4; nf < 8; ++nf) {
            int f = (nf - 4) * 16 + cl;
            float v0 = lrelu(acc[nf][0]);
            float v1 = lrelu(acc[nf][1]);
            float v2 = lrelu(acc[nf][2]);
            float v3 = lrelu(acc[nf][3]);
            __hip_bfloat162 q0 = __float22bfloat162_rn(make_float2(v0, v1));
            __hip_bfloat162 q1 = __float22bfloat162_rn(make_float2(v2, v3));
            uint2 pk;
            pk.x = *(unsigned int*)&q0;
            pk.y = *(unsigned int*)&q1;
            *(uint2*)&h2[(((size_t)bb * 64 + f) << 10) + p0] = pk;
        }
    }
}

// ---------------------------------------------------------------------------
// Kernel 2: softmax over batch per pixel; mcT[p][b] -> attnN[b][p]
// ---------------------------------------------------------------------------
__global__ __launch_bounds__(256) void softmax_b(
    const float* __restrict__ mcT, float* __restrict__ attnN)
{
    int p = blockIdx.x, t = threadIdx.x;
    float v = mcT[(size_t)p * BS + t];
    float m = v;
    #pragma unroll
    for (int o = 32; o > 0; o >>= 1) m = fmaxf(m, __shfl_xor(m, o));
    __shared__ float r1[4], r2[4];
    int w = t >> 6, lz = t & 63;
    if (lz == 0) r1[w] = m;
    __syncthreads();
    m = fmaxf(fmaxf(r1[0], r1[1]), fmaxf(r1[2], r1[3]));
    float e = expf(v - m);
    float s = e;
    #pragma unroll
    for (int o = 32; o > 0; o >>= 1) s += __shfl_xor(s, o);
    if (lz == 0) r2[w] = s;
    __syncthreads();
    s = r2[0] + r2[1] + r2[2] + r2[3];
    attnN[(size_t)t * PIX + p] = e / s;
}

// ---------------------------------------------------------------------------
// Kernel 3: neighbour[b,f] = sum_p h2[b][f][p] * attn[b][p]; blend with chalf.
// ---------------------------------------------------------------------------
__global__ __launch_bounds__(256) void neighbour_k(
    const unsigned short* __restrict__ h2, const float* __restrict__ attnN,
    const float* __restrict__ chalf, float* __restrict__ out)
{
    int b = blockIdx.x, tid = threadIdx.x;
    int l = tid & 63, w = tid >> 6;
    __shared__ float att[PIX];
    for (int p = tid; p < PIX; p += 256) att[p] = attnN[(size_t)b * PIX + p];
    __syncthreads();

    float av[16];
    #pragma unroll
    for (int i = 0; i < 8; ++i) av[i]     = att[l * 8 + i];
    #pragma unroll
    for (int i = 0; i < 8; ++i) av[8 + i] = att[512 + l * 8 + i];

    const unsigned short* hb = h2 + ((size_t)b * 64) * 1024;
    for (int j = 0; j < 16; ++j) {
        int f = w * 16 + j;
        const unsigned short* hf = hb + (size_t)f * 1024;
        bf16x8 h0 = *(const bf16x8*)&hf[l * 8];
        bf16x8 h1 = *(const bf16x8*)&hf[512 + l * 8];
        float acc = 0.f;
        #pragma unroll
        for (int i = 0; i < 8; ++i) acc += bf2f(h0[i]) * av[i];
        #pragma unroll
        for (int i = 0; i < 8; ++i) acc += bf2f(h1[i]) * av[8 + i];
        #pragma unroll
        for (int o = 32; o > 0; o >>= 1) acc += __shfl_xor(acc, o);
        if (l == 0)
            out[b * FEAT + f] = chalf[b * FEAT + f] + (1.f - BETA) * acc;
    }
}

// ---------------------------------------------------------------------------
extern "C" void kernel_launch(void* const* d_in, const int* in_sizes, int n_in,
                              void* d_out, int out_size, void* d_ws, size_t ws_size,
                              hipStream_t stream)
{
    const float* x  = (const float*)d_in[0];
    const float* Wk = (const float*)d_in[1];
    const float* Wv = (const float*)d_in[2];
    const float* Wn = (const float*)d_in[3];
    float* out = (float*)d_out;

    float* ws    = (float*)d_ws;
    float* c1    = ws;                                   // 16384 f
    float* chalf = ws + 16384;                           // 16384 f
    float* mcT   = ws + 32768;                           // 262144 f  [p][b]
    float* attnN = ws + 294912;                          // 262144 f  [b][p]
    unsigned short* Wb = (unsigned short*)(ws + 557056); // 28672 u16
    unsigned short* h2 = (unsigned short*)((char*)d_ws + 2285568); // 33.5 MB

    prep_k   <<<312,  64, 0, stream>>>(x, Wk, Wv, Wn, Wb, c1, chalf);
    gemm_mfma<<<4096, 256, 0, stream>>>(x, Wb, c1, mcT, h2);
    softmax_b<<<PIX,  256, 0, stream>>>(mcT, attnN);
    neighbour_k<<<BS, 256, 0, stream>>>(h2, attnN, chalf, out);
}

// Round 4
// 79.632 us; speedup vs baseline: 3.2804x; 1.2918x over previous
//
#include <hip/hip_runtime.h>
#include <hip/hip_bf16.h>

#define BS    256
#define PIX   1024
#define CBAND 200
#define NK    7            // K-steps of 32 (K padded 200 -> 224)
#define FEAT  64
#define ALPHA 0.2f
#define BETA  0.5f
#define XSTR  232          // LDS row stride in bf16 elems (16B-aligned, 2-way=free)

typedef __attribute__((ext_vector_type(8))) short bf16x8;   // MFMA A/B fragment
typedef __attribute__((ext_vector_type(4))) float f32x4;    // MFMA C/D fragment

__device__ __forceinline__ float lrelu(float v) { return v >= 0.f ? v : ALPHA * v; }
__device__ __forceinline__ float bf2f(short s) {
    unsigned int u = ((unsigned int)(unsigned short)s) << 16;
    return __uint_as_float(u);
}

// ---------------------------------------------------------------------------
// Kernel 0 (fused prep), 256 threads/block.
// Blocks 0..13: pack Wk||Wv into bf16 B-fragments (4 sub-blocks each).
//   Wb[((ks*8+nf)*64 + lane)*8 + i] = W[k][c], k = ks*32+(lane>>4)*8+i,
//   c = nf*16+(lane&15), zero for k >= 200.
// Blocks 14..269: central-pixel features (fp32 exact), K-loop split 4 ways.
// ---------------------------------------------------------------------------
__global__ __launch_bounds__(256) void prep_k(
    const float* __restrict__ x, const float* __restrict__ Wk,
    const float* __restrict__ Wv, const float* __restrict__ Wn,
    unsigned short* __restrict__ Wb, float* __restrict__ c1,
    float* __restrict__ chalf)
{
    const int tid = threadIdx.x;
    if (blockIdx.x < 14) {
        int bid2 = blockIdx.x * 4 + (tid >> 6);   // 0..55
        int l  = tid & 63;
        int nf = bid2 & 7;
        int ks = bid2 >> 3;
        int c  = nf * 16 + (l & 15);
        int k0 = ks * 32 + (l >> 4) * 8;
        __attribute__((aligned(16))) unsigned short o[8];
        #pragma unroll
        for (int i = 0; i < 8; ++i) {
            int k = k0 + i;
            float w = 0.f;
            if (k < CBAND) w = (c < 64) ? Wk[k * 64 + c] : Wv[k * 64 + (c - 64)];
            unsigned int u = __float_as_uint(w);
            u += 0x7FFFu + ((u >> 16) & 1u);      // RNE to bf16
            o[i] = (unsigned short)(u >> 16);
        }
        *(uint4*)&Wb[((size_t)bid2 * 64 + l) * 8] = *(uint4*)o;
        return;
    }
    __shared__ float xr[CBAND];
    __shared__ float part[2][4][FEAT];
    __shared__ float c2s[FEAT];
    int b = blockIdx.x - 14;
    int f = tid & 63, q = tid >> 6;
    const float* xc = x + (size_t)b * (PIX * CBAND) + (16 * 32 + 16) * CBAND;
    for (int c = tid; c < CBAND; c += 256) xr[c] = xc[c];
    __syncthreads();
    float a1 = 0.f, a2 = 0.f;
    #pragma unroll 5
    for (int c = q * 50; c < q * 50 + 50; ++c) {
        float xv = xr[c];
        a1 += xv * Wk[c * FEAT + f];
        a2 += xv * Wv[c * FEAT + f];
    }
    part[0][q][f] = a1;
    part[1][q][f] = a2;
    __syncthreads();
    if (tid < FEAT) {
        float s1 = part[0][0][f] + part[0][1][f] + part[0][2][f] + part[0][3][f];
        float s2 = part[1][0][f] + part[1][1][f] + part[1][2][f] + part[1][3][f];
        c1[b * FEAT + f] = lrelu(s1);
        c2s[f] = lrelu(s2);
    }
    __syncthreads();
    if (tid < FEAT) {
        float a3 = 0.f;
        #pragma unroll 8
        for (int g = 0; g < FEAT; ++g) a3 += c2s[g] * Wn[f * FEAT + g];
        chalf[b * FEAT + f] = BETA * lrelu(a3);
    }
}

// ---------------------------------------------------------------------------
// Kernel 1: MFMA GEMM. 262144 rows x K=224(pad) x N=128.
// Block: 64 rows, 4 waves. Wave tile: 32 rows x 64 cols:
//   wave w -> rows (w&1)*32..+31, N-frags nf0=(w>>1)*4..+3
//   (w=0,1: h1 cols 0..63; w=2,3: h2 cols 64..127)
// Halves per-wave B traffic vs 16-row waves (0.94 GB -> 0.47 GB via L2).
// Epilogue: h1 waves -> mean_corr [p][b]; h2 waves -> h2[b][f][p] bf16.
// ---------------------------------------------------------------------------
__global__ __launch_bounds__(256, 4) void gemm_mfma(
    const float* __restrict__ x, const unsigned short* __restrict__ Wb,
    const float* __restrict__ c1, float* __restrict__ mcT,
    unsigned short* __restrict__ h2)
{
    __shared__ unsigned short xs[64 * XSTR];
    __shared__ float c1s[FEAT];

    const int tid  = threadIdx.x;
    const int l    = tid & 63;
    const int w    = tid >> 6;
    const int row0 = blockIdx.x * 64;
    const int bb   = row0 >> 10;          // one batch per block

    const int nf0   = (w >> 1) * 4;       // 0 (h1) or 4 (h2)
    const int mrow0 = (w & 1) * 32;

    const bf16x8* wbv = (const bf16x8*)Wb;
    bf16x8 bq[2][4];
    #pragma unroll
    for (int nj = 0; nj < 4; ++nj) bq[0][nj] = wbv[(nf0 + nj) * 64 + l];  // ks=0

    // stage x tile (64 rows x 200 f32) -> bf16 LDS, linear float4 stream
    for (int idx = tid; idx < 64 * 50; idx += 256) {
        int row = idx / 50;
        int c4  = idx - row * 50;
        float4 v = *(const float4*)(x + (size_t)(row0 + row) * CBAND + c4 * 4);
        __hip_bfloat162 p0 = __float22bfloat162_rn(make_float2(v.x, v.y));
        __hip_bfloat162 p1 = __float22bfloat162_rn(make_float2(v.z, v.w));
        uint2 pk;
        pk.x = *(unsigned int*)&p0;
        pk.y = *(unsigned int*)&p1;
        *(uint2*)&xs[row * XSTR + c4 * 4] = pk;
    }
    if (tid < 64) {                       // zero-pad k in [200, 232)
        uint4 z = make_uint4(0, 0, 0, 0);
        #pragma unroll
        for (int q = 0; q < 4; ++q) *(uint4*)&xs[tid * XSTR + 200 + q * 8] = z;
    }
    if (tid < FEAT) c1s[tid] = c1[bb * FEAT + tid];
    __syncthreads();

    f32x4 acc[2][4];
    #pragma unroll
    for (int mi = 0; mi < 2; ++mi)
        #pragma unroll
        for (int nj = 0; nj < 4; ++nj) acc[mi][nj] = (f32x4){0.f, 0.f, 0.f, 0.f};

    const int arow = mrow0 + (l & 15);
    const int kofs = (l >> 4) * 8;

    #pragma unroll
    for (int ks = 0; ks < NK; ++ks) {
        if (ks + 1 < NK) {
            #pragma unroll
            for (int nj = 0; nj < 4; ++nj)
                bq[(ks + 1) & 1][nj] = wbv[((ks + 1) * 8 + nf0 + nj) * 64 + l];
        }
        bf16x8 a0 = *(const bf16x8*)&xs[arow * XSTR + ks * 32 + kofs];
        bf16x8 a1 = *(const bf16x8*)&xs[(arow + 16) * XSTR + ks * 32 + kofs];
        #pragma unroll
        for (int nj = 0; nj < 4; ++nj) {
            bf16x8 b = bq[ks & 1][nj];
            acc[0][nj] = __builtin_amdgcn_mfma_f32_16x16x32_bf16(a0, b, acc[0][nj], 0, 0, 0);
            acc[1][nj] = __builtin_amdgcn_mfma_f32_16x16x32_bf16(a1, b, acc[1][nj], 0, 0, 0);
        }
    }

    // ---- epilogue ----
    const int g  = l >> 4;                // D row group
    const int cl = l & 15;                // D col within fragment

    if (nf0 == 0) {
        // h1 waves: mean_corr[p][b] = mean_f(lrelu(h1) * c1)
        #pragma unroll
        for (int mi = 0; mi < 2; ++mi) {
            #pragma unroll
            for (int r = 0; r < 4; ++r) {
                float part = 0.f;
                #pragma unroll
                for (int nj = 0; nj < 4; ++nj)
                    part += lrelu(acc[mi][nj][r]) * c1s[nj * 16 + cl];
                part += __shfl_xor(part, 1);
                part += __shfl_xor(part, 2);
                part += __shfl_xor(part, 4);
                part += __shfl_xor(part, 8);
                if (cl == 0) {
                    int grow = row0 + mrow0 + mi * 16 + g * 4 + r;
                    int p = grow & (PIX - 1);
                    mcT[(size_t)p * BS + bb] = part * (1.f / 64.f);
                }
            }
        }
    } else {
        // h2 waves: store lrelu as bf16, layout h2[b][f][p]; 4 consecutive p
        #pragma unroll
        for (int mi = 0; mi < 2; ++mi) {
            int p0 = (row0 & (PIX - 1)) + mrow0 + mi * 16 + g * 4;
            #pragma unroll
            for (int nj = 0; nj < 4; ++nj) {
                int f = nj * 16 + cl;
                float v0 = lrelu(acc[mi][nj][0]);
                float v1 = lrelu(acc[mi][nj][1]);
                float v2 = lrelu(acc[mi][nj][2]);
                float v3 = lrelu(acc[mi][nj][3]);
                __hip_bfloat162 q0 = __float22bfloat162_rn(make_float2(v0, v1));
                __hip_bfloat162 q1 = __float22bfloat162_rn(make_float2(v2, v3));
                uint2 pk;
                pk.x = *(unsigned int*)&q0;
                pk.y = *(unsigned int*)&q1;
                *(uint2*)&h2[(((size_t)bb * 64 + f) << 10) + p0] = pk;
            }
        }
    }
}

// ---------------------------------------------------------------------------
// Kernel 2: softmax over batch per pixel; mcT[p][b] -> attnN[b][p]
// ---------------------------------------------------------------------------
__global__ __launch_bounds__(256) void softmax_b(
    const float* __restrict__ mcT, float* __restrict__ attnN)
{
    int p = blockIdx.x, t = threadIdx.x;
    float v = mcT[(size_t)p * BS + t];
    float m = v;
    #pragma unroll
    for (int o = 32; o > 0; o >>= 1) m = fmaxf(m, __shfl_xor(m, o));
    __shared__ float r1[4], r2[4];
    int w = t >> 6, lz = t & 63;
    if (lz == 0) r1[w] = m;
    __syncthreads();
    m = fmaxf(fmaxf(r1[0], r1[1]), fmaxf(r1[2], r1[3]));
    float e = expf(v - m);
    float s = e;
    #pragma unroll
    for (int o = 32; o > 0; o >>= 1) s += __shfl_xor(s, o);
    if (lz == 0) r2[w] = s;
    __syncthreads();
    s = r2[0] + r2[1] + r2[2] + r2[3];
    attnN[(size_t)t * PIX + p] = e / s;
}

// ---------------------------------------------------------------------------
// Kernel 3: neighbour[b,f] = sum_p h2[b][f][p] * attn[b][p]; blend with chalf.
// 1024 threads (16 waves) per block; wave handles 4 f values.
// ---------------------------------------------------------------------------
__global__ __launch_bounds__(1024) void neighbour_k(
    const unsigned short* __restrict__ h2, const float* __restrict__ attnN,
    const float* __restrict__ chalf, float* __restrict__ out)
{
    int b = blockIdx.x, tid = threadIdx.x;
    int l = tid & 63, w = tid >> 6;       // 16 waves
    __shared__ float att[PIX];
    if (tid < PIX) att[tid] = attnN[(size_t)b * PIX + tid];
    __syncthreads();

    float av[16];
    #pragma unroll
    for (int i = 0; i < 8; ++i) av[i]     = att[l * 8 + i];
    #pragma unroll
    for (int i = 0; i < 8; ++i) av[8 + i] = att[512 + l * 8 + i];

    const unsigned short* hb = h2 + ((size_t)b * 64) * 1024;
    #pragma unroll
    for (int j = 0; j < 4; ++j) {
        int f = w * 4 + j;
        const unsigned short* hf = hb + (size_t)f * 1024;
        bf16x8 h0 = *(const bf16x8*)&hf[l * 8];
        bf16x8 h1 = *(const bf16x8*)&hf[512 + l * 8];
        float acc = 0.f;
        #pragma unroll
        for (int i = 0; i < 8; ++i) acc += bf2f(h0[i]) * av[i];
        #pragma unroll
        for (int i = 0; i < 8; ++i) acc += bf2f(h1[i]) * av[8 + i];
        #pragma unroll
        for (int o = 32; o > 0; o >>= 1) acc += __shfl_xor(acc, o);
        if (l == 0)
            out[b * FEAT + f] = chalf[b * FEAT + f] + (1.f - BETA) * acc;
    }
}

// ---------------------------------------------------------------------------
extern "C" void kernel_launch(void* const* d_in, const int* in_sizes, int n_in,
                              void* d_out, int out_size, void* d_ws, size_t ws_size,
                              hipStream_t stream)
{
    const float* x  = (const float*)d_in[0];
    const float* Wk = (const float*)d_in[1];
    const float* Wv = (const float*)d_in[2];
    const float* Wn = (const float*)d_in[3];
    float* out = (float*)d_out;

    float* ws    = (float*)d_ws;
    float* c1    = ws;                                   // 16384 f
    float* chalf = ws + 16384;                           // 16384 f
    float* mcT   = ws + 32768;                           // 262144 f  [p][b]
    float* attnN = ws + 294912;                          // 262144 f  [b][p]
    unsigned short* Wb = (unsigned short*)(ws + 557056); // 28672 u16
    unsigned short* h2 = (unsigned short*)((char*)d_ws + 2285568); // 33.5 MB

    prep_k   <<<270,  256, 0, stream>>>(x, Wk, Wv, Wn, Wb, c1, chalf);
    gemm_mfma<<<4096, 256, 0, stream>>>(x, Wb, c1, mcT, h2);
    softmax_b<<<PIX,  256, 0, stream>>>(mcT, attnN);
    neighbour_k<<<BS, 1024, 0, stream>>>(h2, attnN, chalf, out);
}

// Round 5
// 74.837 us; speedup vs baseline: 3.4906x; 1.0641x over previous
//
#include <hip/hip_runtime.h>
#include <hip/hip_bf16.h>

#define BS    256
#define PIX   1024
#define CBAND 200
#define NK    7            // K-steps of 32 (K 200 -> 224; tail k>=200 hits B=0)
#define FEAT  64
#define ALPHA 0.2f
#define BETA  0.5f
#define TROWS 32           // rows per K-tile
#define TBYTES (TROWS * CBAND * 4)   // 25600 B = 25 x 1KB wave-chunks
#define NTILE 4            // tiles per block (128 rows/block, grid 2048)
#define SLACK 128          // LDS slack so ks=6 tail reads stay in-bounds (zeroed)

typedef __attribute__((ext_vector_type(8))) short bf16x8;   // MFMA A/B fragment
typedef __attribute__((ext_vector_type(4))) float f32x4;    // MFMA C/D fragment

__device__ __forceinline__ float lrelu(float v) { return v >= 0.f ? v : ALPHA * v; }
__device__ __forceinline__ float bf2f(short s) {
    unsigned int u = ((unsigned int)(unsigned short)s) << 16;
    return __uint_as_float(u);
}
__device__ __forceinline__ unsigned int pkbf(float a, float b) {
    __hip_bfloat162 t = __float22bfloat162_rn(make_float2(a, b));
    return *(unsigned int*)&t;
}
// async global->LDS, 16B per lane; LDS dest = uniform base + lane*16
__device__ __forceinline__ void load_lds16(const void* g, void* l) {
    __builtin_amdgcn_global_load_lds(
        (const __attribute__((address_space(1))) void*)g,
        (__attribute__((address_space(3))) void*)l, 16, 0, 0);
}

// ---------------------------------------------------------------------------
// Kernel 0 (fused prep), 256 threads/block.
// Blocks 0..13: pack Wk||Wv into bf16 B-fragments.
//   Wb[((ks*8+nf)*64 + lane)*8 + i] = W[k][c], k = ks*32+(lane>>4)*8+i,
//   c = nf*16+(lane&15), zero for k >= 200.
// Blocks 14..269: central-pixel features (fp32 exact), K split 4 ways.
// ---------------------------------------------------------------------------
__global__ __launch_bounds__(256) void prep_k(
    const float* __restrict__ x, const float* __restrict__ Wk,
    const float* __restrict__ Wv, const float* __restrict__ Wn,
    unsigned short* __restrict__ Wb, float* __restrict__ c1,
    float* __restrict__ chalf)
{
    const int tid = threadIdx.x;
    if (blockIdx.x < 14) {
        int bid2 = blockIdx.x * 4 + (tid >> 6);   // 0..55
        int l  = tid & 63;
        int nf = bid2 & 7;
        int ks = bid2 >> 3;
        int c  = nf * 16 + (l & 15);
        int k0 = ks * 32 + (l >> 4) * 8;
        __attribute__((aligned(16))) unsigned short o[8];
        #pragma unroll
        for (int i = 0; i < 8; ++i) {
            int k = k0 + i;
            float w = 0.f;
            if (k < CBAND) w = (c < 64) ? Wk[k * 64 + c] : Wv[k * 64 + (c - 64)];
            unsigned int u = __float_as_uint(w);
            u += 0x7FFFu + ((u >> 16) & 1u);      // RNE to bf16
            o[i] = (unsigned short)(u >> 16);
        }
        *(uint4*)&Wb[((size_t)bid2 * 64 + l) * 8] = *(uint4*)o;
        return;
    }
    __shared__ float xr[CBAND];
    __shared__ float part[2][4][FEAT];
    __shared__ float c2s[FEAT];
    int b = blockIdx.x - 14;
    int f = tid & 63, q = tid >> 6;
    const float* xc = x + (size_t)b * (PIX * CBAND) + (16 * 32 + 16) * CBAND;
    for (int c = tid; c < CBAND; c += 256) xr[c] = xc[c];
    __syncthreads();
    float a1 = 0.f, a2 = 0.f;
    #pragma unroll 5
    for (int c = q * 50; c < q * 50 + 50; ++c) {
        float xv = xr[c];
        a1 += xv * Wk[c * FEAT + f];
        a2 += xv * Wv[c * FEAT + f];
    }
    part[0][q][f] = a1;
    part[1][q][f] = a2;
    __syncthreads();
    if (tid < FEAT) {
        float s1 = part[0][0][f] + part[0][1][f] + part[0][2][f] + part[0][3][f];
        float s2 = part[1][0][f] + part[1][1][f] + part[1][2][f] + part[1][3][f];
        c1[b * FEAT + f] = lrelu(s1);
        c2s[f] = lrelu(s2);
    }
    __syncthreads();
    if (tid < FEAT) {
        float a3 = 0.f;
        #pragma unroll 8
        for (int g = 0; g < FEAT; ++g) a3 += c2s[g] * Wn[f * FEAT + g];
        chalf[b * FEAT + f] = BETA * lrelu(a3);
    }
}

// ---------------------------------------------------------------------------
// Kernel 1: MFMA GEMM, DMA-staged + double-buffered.
// Block: 4 tiles x 32 rows, 4 waves. Wave w -> N-frags {2w, 2w+1} (w0,w1 = h1
// cols; w2,w3 = h2 cols), all 32 rows of the tile.
// - x tile staged as RAW FP32 via global_load_lds (25 linear 1KB chunks),
//   double-buffered; one __syncthreads per tile (vmcnt drain = stage fence).
// - B fragments register-resident for the whole block (14 frags, 56 VGPR).
// - fp32->bf16 cvt at A-fragment read (cvt_pk); k>=200 tail garbage x B=0.
// - h1 f-mean spans waves 0,1 -> LDS partials, ping-pong, combined next tile.
// ---------------------------------------------------------------------------
__global__ __launch_bounds__(256) void gemm_mfma(
    const float* __restrict__ x, const unsigned short* __restrict__ Wb,
    const float* __restrict__ c1, float* __restrict__ mcT,
    unsigned short* __restrict__ h2)
{
    __shared__ __align__(16) float xbuf[2][(TBYTES + SLACK) / 4];
    __shared__ float c1s[FEAT];
    __shared__ float hpart[2][2][TROWS];

    const int tid = threadIdx.x;
    const int l   = tid & 63;
    const int w   = tid >> 6;
    const int bb  = blockIdx.x >> 3;              // 8 blocks per batch
    const int pbase = (blockIdx.x & 7) * (TROWS * NTILE);
    const size_t row0 = (size_t)blockIdx.x * (TROWS * NTILE);

    // zero the tail slack once (NaN-proof the ks=6 garbage reads)
    if (tid < SLACK / 4) {
        xbuf[0][TBYTES / 4 + tid] = 0.f;
        xbuf[1][TBYTES / 4 + tid] = 0.f;
    }
    if (tid < FEAT) c1s[tid] = c1[bb * FEAT + tid];

    // resident B fragments: wave w covers nf0=2w, nf0+1 for all 7 ks
    const bf16x8* wbv = (const bf16x8*)Wb;
    const int nf0 = 2 * w;
    bf16x8 bq[NK][2];
    #pragma unroll
    for (int ks = 0; ks < NK; ++ks)
        #pragma unroll
        for (int nj = 0; nj < 2; ++nj)
            bq[ks][nj] = wbv[(ks * 8 + nf0 + nj) * 64 + l];

    const char* xbase = (const char*)(x + row0 * CBAND);
    auto stage = [&](int t, int buf) {
        const char* g  = xbase + (size_t)t * TBYTES + l * 16;
        char*       lp = (char*)&xbuf[buf][0];
        for (int c = w; c < 25; c += 4)           // 25 x 1KB linear chunks
            load_lds16(g + c * 1024, lp + c * 1024);
    };
    stage(0, 0);

    const int fr = l & 15;     // fragment row / D col
    const int g4 = l >> 4;     // k subgroup / D row group

    for (int t = 0; t < NTILE; ++t) {
        __syncthreads();                          // drains vmcnt: stage(t) done
        if (t + 1 < NTILE) stage(t + 1, (t + 1) & 1);

        // combine previous tile's h1 partials (wave 3: lightest stage load)
        if (t > 0 && w == 3 && l < TROWS) {
            int p = pbase + (t - 1) * TROWS + l;
            float v = (hpart[(t - 1) & 1][0][l] + hpart[(t - 1) & 1][1][l]) * (1.f / 64.f);
            mcT[(size_t)p * BS + bb] = v;
        }

        const float* xb = &xbuf[t & 1][0];
        f32x4 acc[2][2];
        #pragma unroll
        for (int mi = 0; mi < 2; ++mi)
            #pragma unroll
            for (int nj = 0; nj < 2; ++nj) acc[mi][nj] = (f32x4){0.f, 0.f, 0.f, 0.f};

        #pragma unroll
        for (int ks = 0; ks < NK; ++ks) {
            bf16x8 a[2];
            #pragma unroll
            for (int mi = 0; mi < 2; ++mi) {
                int r = mi * 16 + fr;
                const float* src = xb + r * CBAND + ks * 32 + g4 * 8;
                f32x4 lo = *(const f32x4*)src;
                f32x4 hi = *(const f32x4*)(src + 4);
                union { bf16x8 v; unsigned int u[4]; } af;
                af.u[0] = pkbf(lo[0], lo[1]);
                af.u[1] = pkbf(lo[2], lo[3]);
                af.u[2] = pkbf(hi[0], hi[1]);
                af.u[3] = pkbf(hi[2], hi[3]);
                a[mi] = af.v;
            }
            #pragma unroll
            for (int nj = 0; nj < 2; ++nj) {
                acc[0][nj] = __builtin_amdgcn_mfma_f32_16x16x32_bf16(a[0], bq[ks][nj], acc[0][nj], 0, 0, 0);
                acc[1][nj] = __builtin_amdgcn_mfma_f32_16x16x32_bf16(a[1], bq[ks][nj], acc[1][nj], 0, 0, 0);
            }
        }

        if (w < 2) {
            // h1 waves: partial f-dot with c1, reduce over 16 cols in-wave
            #pragma unroll
            for (int mi = 0; mi < 2; ++mi) {
                #pragma unroll
                for (int r = 0; r < 4; ++r) {
                    float part = 0.f;
                    #pragma unroll
                    for (int nj = 0; nj < 2; ++nj)
                        part += lrelu(acc[mi][nj][r]) * c1s[(nf0 + nj) * 16 + fr];
                    part += __shfl_xor(part, 1);
                    part += __shfl_xor(part, 2);
                    part += __shfl_xor(part, 4);
                    part += __shfl_xor(part, 8);
                    if (fr == 0) hpart[t & 1][w][mi * 16 + g4 * 4 + r] = part;
                }
            }
        } else {
            // h2 waves: store lrelu as bf16, layout h2[b][f][p], 4 p per lane
            #pragma unroll
            for (int mi = 0; mi < 2; ++mi) {
                int p0 = pbase + t * TROWS + mi * 16 + g4 * 4;
                #pragma unroll
                for (int nj = 0; nj < 2; ++nj) {
                    int f = (nf0 + nj - 4) * 16 + fr;
                    uint2 pk;
                    pk.x = pkbf(lrelu(acc[mi][nj][0]), lrelu(acc[mi][nj][1]));
                    pk.y = pkbf(lrelu(acc[mi][nj][2]), lrelu(acc[mi][nj][3]));
                    *(uint2*)&h2[(((size_t)bb * 64 + f) << 10) + p0] = pk;
                }
            }
        }
    }
    __syncthreads();
    if (w == 3 && l < TROWS) {                    // final tile's h1 combine
        int p = pbase + (NTILE - 1) * TROWS + l;
        float v = (hpart[(NTILE - 1) & 1][0][l] + hpart[(NTILE - 1) & 1][1][l]) * (1.f / 64.f);
        mcT[(size_t)p * BS + bb] = v;
    }
}

// ---------------------------------------------------------------------------
// Kernel 2: softmax over batch per pixel; mcT[p][b] -> attnN[b][p]
// ---------------------------------------------------------------------------
__global__ __launch_bounds__(256) void softmax_b(
    const float* __restrict__ mcT, float* __restrict__ attnN)
{
    int p = blockIdx.x, t = threadIdx.x;
    float v = mcT[(size_t)p * BS + t];
    float m = v;
    #pragma unroll
    for (int o = 32; o > 0; o >>= 1) m = fmaxf(m, __shfl_xor(m, o));
    __shared__ float r1[4], r2[4];
    int w = t >> 6, lz = t & 63;
    if (lz == 0) r1[w] = m;
    __syncthreads();
    m = fmaxf(fmaxf(r1[0], r1[1]), fmaxf(r1[2], r1[3]));
    float e = expf(v - m);
    float s = e;
    #pragma unroll
    for (int o = 32; o > 0; o >>= 1) s += __shfl_xor(s, o);
    if (lz == 0) r2[w] = s;
    __syncthreads();
    s = r2[0] + r2[1] + r2[2] + r2[3];
    attnN[(size_t)t * PIX + p] = e / s;
}

// ---------------------------------------------------------------------------
// Kernel 3: neighbour[b,f] = sum_p h2[b][f][p] * attn[b][p]; blend with chalf.
// 1024 threads (16 waves) per block; wave handles 4 f values.
// ---------------------------------------------------------------------------
__global__ __launch_bounds__(1024) void neighbour_k(
    const unsigned short* __restrict__ h2, const float* __restrict__ attnN,
    const float* __restrict__ chalf, float* __restrict__ out)
{
    int b = blockIdx.x, tid = threadIdx.x;
    int l = tid & 63, w = tid >> 6;       // 16 waves
    __shared__ float att[PIX];
    if (tid < PIX) att[tid] = attnN[(size_t)b * PIX + tid];
    __syncthreads();

    float av[16];
    #pragma unroll
    for (int i = 0; i < 8; ++i) av[i]     = att[l * 8 + i];
    #pragma unroll
    for (int i = 0; i < 8; ++i) av[8 + i] = att[512 + l * 8 + i];

    const unsigned short* hb = h2 + ((size_t)b * 64) * 1024;
    #pragma unroll
    for (int j = 0; j < 4; ++j) {
        int f = w * 4 + j;
        const unsigned short* hf = hb + (size_t)f * 1024;
        bf16x8 h0 = *(const bf16x8*)&hf[l * 8];
        bf16x8 h1 = *(const bf16x8*)&hf[512 + l * 8];
        float acc = 0.f;
        #pragma unroll
        for (int i = 0; i < 8; ++i) acc += bf2f(h0[i]) * av[i];
        #pragma unroll
        for (int i = 0; i < 8; ++i) acc += bf2f(h1[i]) * av[8 + i];
        #pragma unroll
        for (int o = 32; o > 0; o >>= 1) acc += __shfl_xor(acc, o);
        if (l == 0)
            out[b * FEAT + f] = chalf[b * FEAT + f] + (1.f - BETA) * acc;
    }
}

// ---------------------------------------------------------------------------
extern "C" void kernel_launch(void* const* d_in, const int* in_sizes, int n_in,
                              void* d_out, int out_size, void* d_ws, size_t ws_size,
                              hipStream_t stream)
{
    const float* x  = (const float*)d_in[0];
    const float* Wk = (const float*)d_in[1];
    const float* Wv = (const float*)d_in[2];
    const float* Wn = (const float*)d_in[3];
    float* out = (float*)d_out;

    float* ws    = (float*)d_ws;
    float* c1    = ws;                                   // 16384 f
    float* chalf = ws + 16384;                           // 16384 f
    float* mcT   = ws + 32768;                           // 262144 f  [p][b]
    float* attnN = ws + 294912;                          // 262144 f  [b][p]
    unsigned short* Wb = (unsigned short*)(ws + 557056); // 28672 u16
    unsigned short* h2 = (unsigned short*)((char*)d_ws + 2285568); // 33.5 MB

    prep_k   <<<270,  256, 0, stream>>>(x, Wk, Wv, Wn, Wb, c1, chalf);
    gemm_mfma<<<2048, 256, 0, stream>>>(x, Wb, c1, mcT, h2);
    softmax_b<<<PIX,  256, 0, stream>>>(mcT, attnN);
    neighbour_k<<<BS, 1024, 0, stream>>>(h2, attnN, chalf, out);
}